// Round 15
// baseline (288.737 us; speedup 1.0000x reference)
//
#include <hip/hip_runtime.h>

typedef _Float16 f16;
typedef _Float16 f16x8 __attribute__((ext_vector_type(8)));
typedef _Float16 f16x4 __attribute__((ext_vector_type(4)));
typedef _Float16 f16x2 __attribute__((ext_vector_type(2)));
typedef float f32x4 __attribute__((ext_vector_type(4)));
typedef int i32x4 __attribute__((ext_vector_type(4)));

#define GLOAD_LDS16(g, l) \
    __builtin_amdgcn_global_load_lds((const __attribute__((address_space(1))) void*)(g), \
                                     (__attribute__((address_space(3))) void*)(l), 16, 0, 0)

__device__ __forceinline__ f16x2 cvt_pk_f16(float a, float b) {
    return __builtin_bit_cast(f16x2, __builtin_amdgcn_cvt_pkrtz(a, b));
}

// 0.125 * log2(e): Qp is pre-scaled by this so attn uses exp2(acc) directly
#define SC_LOG2E 0.180336880f

// ---------------- merged prep (no maskbits — that overlaps with proj) ----------------
// bid<12288: q/k/v cvt | <13056: Wq/Wk/Wv LDS-transpose | <13312: Wo LDS-transpose
__global__ __launch_bounds__(256) void prep_kernel(const float* __restrict__ q,
        const float* __restrict__ k, const float* __restrict__ v,
        const float* __restrict__ Wq, const float* __restrict__ Wk,
        const float* __restrict__ Wv, const float* __restrict__ Wo,
        f16* __restrict__ qh, f16* __restrict__ wt) {
    __shared__ float tile[64][68];
    const int bid = blockIdx.x;
    const int tid = threadIdx.x;
    if (bid < 12288) {
        const int z = bid >> 12;
        const float* src = (z == 0) ? q : (z == 1) ? k : v;
        const size_t i = ((size_t)(bid & 4095) * 256 + tid) * 8;
        float4 a = *(const float4*)&src[i], b2 = *(const float4*)&src[i + 4];
        f16x8 h;
        h[0] = (f16)a.x; h[1] = (f16)a.y; h[2] = (f16)a.z; h[3] = (f16)a.w;
        h[4] = (f16)b2.x; h[5] = (f16)b2.y; h[6] = (f16)b2.z; h[7] = (f16)b2.w;
        *(f16x8*)&qh[(size_t)z * 8388608 + i] = h;
    } else if (bid < 13056) {
        // Wq/Wk/Wv: [h, d, kk] -> wt[z][n=h*64+kk][d], 64x64 tile over (d, kk)
        const int t2 = bid - 12288;
        const int z = t2 >> 8;
        const int rem = t2 & 255;
        const int h = rem >> 4, d0 = (rem & 15) * 64;
        const float* W = (z == 0) ? Wq : (z == 1) ? Wk : Wv;
        const int rr = tid >> 4, c4 = (tid & 15) * 4;
#pragma unroll
        for (int i = 0; i < 4; ++i) {
            const int dd = rr + 16 * i;
            *(float4*)&tile[dd][c4] = *(const float4*)&W[((size_t)h * 1024 + d0 + dd) * 64 + c4];
        }
        __syncthreads();
#pragma unroll
        for (int i = 0; i < 4; ++i) {
            const int kk = rr + 16 * i;
            f16x4 hv;
            hv[0] = (f16)tile[c4 + 0][kk];
            hv[1] = (f16)tile[c4 + 1][kk];
            hv[2] = (f16)tile[c4 + 2][kk];
            hv[3] = (f16)tile[c4 + 3][kk];
            *(f16x4*)&wt[(size_t)z * 1048576 + (size_t)(h * 64 + kk) * 1024 + d0 + c4] = hv;
        }
    } else {
        // Wo: [d][n] -> wt[3][n][d], 64x64 tile over (d, n)
        const int rem = bid - 13056;
        const int d0 = (rem >> 4) * 64, n0 = (rem & 15) * 64;
        const int rr = tid >> 4, c4 = (tid & 15) * 4;
#pragma unroll
        for (int i = 0; i < 4; ++i) {
            const int dd = rr + 16 * i;
            *(float4*)&tile[dd][c4] = *(const float4*)&Wo[(size_t)(d0 + dd) * 1024 + n0 + c4];
        }
        __syncthreads();
#pragma unroll
        for (int i = 0; i < 4; ++i) {
            const int nn = rr + 16 * i;
            f16x4 hv;
            hv[0] = (f16)tile[c4 + 0][nn];
            hv[1] = (f16)tile[c4 + 1][nn];
            hv[2] = (f16)tile[c4 + 2][nn];
            hv[3] = (f16)tile[c4 + 3][nn];
            *(f16x4*)&wt[(size_t)3 * 1048576 + (size_t)(n0 + nn) * 1024 + d0 + c4] = hv;
        }
    }
}

// ---------------- fused Q/K/V projection GEMM + overlapped maskbits -----------------
__global__ __launch_bounds__(256) void proj_kernel(const f16* __restrict__ Ah,
        const f16* __restrict__ Wt, f16* __restrict__ Outp,
        const int* __restrict__ mask, unsigned* __restrict__ bits) {
    __shared__ __align__(16) f16 As[128][64];
    __shared__ __align__(16) f16 Bs[128][64];
    const int id = blockIdx.x;
    const int tid = threadIdx.x;
    if (id >= 1536) {
        const int t = (id - 1536) * 256 + tid;
        const i32x4* src = (const i32x4*)mask + (size_t)t * 8;
        unsigned w = 0;
#pragma unroll
        for (int i = 0; i < 8; ++i) {
            i32x4 vv = __builtin_nontemporal_load(src + i);   // don't evict qh/Qp from L2/L3
            w |= (vv.x != 0 ? 1u : 0u) << (i * 4 + 0);
            w |= (vv.y != 0 ? 1u : 0u) << (i * 4 + 1);
            w |= (vv.z != 0 ? 1u : 0u) << (i * 4 + 2);
            w |= (vv.w != 0 ? 1u : 0u) << (i * 4 + 3);
        }
        bits[t] = w;
        return;
    }
    const int z = id >> 9;
    const int id2 = id & 511;
    const int m0 = ((id2 & 7) * 8 + ((id2 >> 3) & 7)) * 128;
    const int n0 = (id2 >> 6) * 128;
    const f16* A = Ah + (size_t)z * 8388608;
    const f16* Bt = Wt + (size_t)z * 1048576;
    f16* Out = Outp + (size_t)z * 8388608;
    const int lane = tid & 63;
    const int w = tid >> 6, wr = w >> 1, wc = w & 1;

    f32x4 acc[4][4];
#pragma unroll
    for (int mi = 0; mi < 4; ++mi)
#pragma unroll
        for (int ni = 0; ni < 4; ++ni) acc[mi][ni] = (f32x4){0.f, 0.f, 0.f, 0.f};

    for (int kt = 0; kt < 16; ++kt) {
        const int k0 = kt * 64;
#pragma unroll
        for (int seg = 0; seg < 4; ++seg) {
            const int ch = seg * 256 + tid, r = ch >> 3, c = ch & 7;
            GLOAD_LDS16(&A[(size_t)(m0 + r) * 1024 + k0 + (c ^ (r & 7)) * 8],
                        (char*)&As[0][0] + (seg * 256 + w * 64) * 16);
            GLOAD_LDS16(&Bt[(size_t)(n0 + r) * 1024 + k0 + (c ^ (r & 7)) * 8],
                        (char*)&Bs[0][0] + (seg * 256 + w * 64) * 16);
        }
        __syncthreads();
#pragma unroll
        for (int ks = 0; ks < 2; ++ks) {
            const int slot = ks * 4 + (lane >> 4);
            f16x8 af[4], bf[4];
#pragma unroll
            for (int mi = 0; mi < 4; ++mi) {
                const int row = wr * 64 + mi * 16 + (lane & 15);
                af[mi] = *(const f16x8*)&As[row][(slot ^ (row & 7)) * 8];
            }
#pragma unroll
            for (int ni = 0; ni < 4; ++ni) {
                const int row = wc * 64 + ni * 16 + (lane & 15);
                bf[ni] = *(const f16x8*)&Bs[row][(slot ^ (row & 7)) * 8];
            }
#pragma unroll
            for (int mi = 0; mi < 4; ++mi)
#pragma unroll
                for (int ni = 0; ni < 4; ++ni)
                    acc[mi][ni] = __builtin_amdgcn_mfma_f32_16x16x32_f16(af[mi], bf[ni], acc[mi][ni], 0, 0, 0);
        }
        __syncthreads();
    }

    const float sc = (z == 0) ? SC_LOG2E : 1.0f;
#pragma unroll
    for (int mi = 0; mi < 4; ++mi)
#pragma unroll
        for (int ni = 0; ni < 4; ++ni) {
            const int row0 = m0 + wr * 64 + mi * 16 + ((lane >> 4) << 2);
            const int col = n0 + wc * 64 + ni * 16 + (lane & 15);
            const int h = col >> 6, kk = col & 63;
            const int b = row0 >> 10, l0 = row0 & 1023;
            if (z < 2) {
#pragma unroll
                for (int r = 0; r < 4; ++r)
                    Out[(((size_t)(b * 16 + h) * 1024) + l0 + r) * 64 + kk] = (f16)(acc[mi][ni][r] * sc);
            } else {
                f16x4 hv;
#pragma unroll
                for (int r = 0; r < 4; ++r) hv[r] = (f16)acc[mi][ni][r];
                *(f16x4*)&Out[((size_t)(b * 16 + h) * 64 + kk) * 1024 + l0] = hv;
            }
        }
}

// ---------------- output projection GEMM: out0 = hc @ Wo^T + bo (f32, nt stores) --------
__global__ __launch_bounds__(256) void out_kernel(const f16* __restrict__ A,
        const f16* __restrict__ Bt, float* __restrict__ O, const float* __restrict__ bias) {
    __shared__ __align__(16) f16 As[128][64];
    __shared__ __align__(16) f16 Bs[128][64];
    const int id2 = blockIdx.x;
    const int m0 = ((id2 & 7) * 8 + ((id2 >> 3) & 7)) * 128;
    const int n0 = (id2 >> 6) * 128;
    const int tid = threadIdx.x, lane = tid & 63;
    const int w = tid >> 6, wr = w >> 1, wc = w & 1;

    f32x4 acc[4][4];
#pragma unroll
    for (int mi = 0; mi < 4; ++mi)
#pragma unroll
        for (int ni = 0; ni < 4; ++ni) acc[mi][ni] = (f32x4){0.f, 0.f, 0.f, 0.f};

    for (int kt = 0; kt < 16; ++kt) {
        const int k0 = kt * 64;
#pragma unroll
        for (int seg = 0; seg < 4; ++seg) {
            const int ch = seg * 256 + tid, r = ch >> 3, c = ch & 7;
            GLOAD_LDS16(&A[(size_t)(m0 + r) * 1024 + k0 + (c ^ (r & 7)) * 8],
                        (char*)&As[0][0] + (seg * 256 + w * 64) * 16);
            GLOAD_LDS16(&Bt[(size_t)(n0 + r) * 1024 + k0 + (c ^ (r & 7)) * 8],
                        (char*)&Bs[0][0] + (seg * 256 + w * 64) * 16);
        }
        __syncthreads();
#pragma unroll
        for (int ks = 0; ks < 2; ++ks) {
            const int slot = ks * 4 + (lane >> 4);
            f16x8 af[4], bf[4];
#pragma unroll
            for (int mi = 0; mi < 4; ++mi) {
                const int row = wr * 64 + mi * 16 + (lane & 15);
                af[mi] = *(const f16x8*)&As[row][(slot ^ (row & 7)) * 8];
            }
#pragma unroll
            for (int ni = 0; ni < 4; ++ni) {
                const int row = wc * 64 + ni * 16 + (lane & 15);
                bf[ni] = *(const f16x8*)&Bs[row][(slot ^ (row & 7)) * 8];
            }
#pragma unroll
            for (int mi = 0; mi < 4; ++mi)
#pragma unroll
                for (int ni = 0; ni < 4; ++ni)
                    acc[mi][ni] = __builtin_amdgcn_mfma_f32_16x16x32_f16(af[mi], bf[ni], acc[mi][ni], 0, 0, 0);
        }
        __syncthreads();
    }

#pragma unroll
    for (int mi = 0; mi < 4; ++mi)
#pragma unroll
        for (int ni = 0; ni < 4; ++ni) {
            const int row0 = m0 + wr * 64 + mi * 16 + ((lane >> 4) << 2);
            const int col = n0 + wc * 64 + ni * 16 + (lane & 15);
            const float bb = bias[col];
#pragma unroll
            for (int r = 0; r < 4; ++r)
                __builtin_nontemporal_store(acc[mi][ni][r] + bb, &O[(size_t)(row0 + r) * 1024 + col]);
        }
}

// ---------------- fused attention: LDS diet (no Qs, no bm) -> 2 blocks/CU ---------------
// Q frags direct global->reg (read-once); mask words direct from L2-resident bits per j.
__global__ __launch_bounds__(512, 4) void attn_fused_kernel(const f16* __restrict__ Qp,
        const f16* __restrict__ Kp, const f16* __restrict__ VpT,
        const unsigned* __restrict__ bits, float* __restrict__ attn, f16* __restrict__ headcat) {
    __shared__ __align__(16) f16 Ks[2][64][64];
    __shared__ __align__(16) f16 Vs[64][64];          // single buffer
    __shared__ __align__(16) f16 Ps[128][64];
    __shared__ __align__(16) float LUTf[16][4];
    __shared__ __align__(16) f16 LUTh[16][4];
    const int bh = blockIdx.x & 127, m0 = (blockIdx.x >> 7) * 128;
    const int b = bh >> 4, h = bh & 15;
    const int tid = threadIdx.x, lane = tid & 63, w = tid >> 6;  // w in [0,8)
    const int l15 = lane & 15, t4 = lane >> 4;
    const f16* Qbase = Qp + (size_t)bh * 65536;
    const f16* Kbase = Kp + (size_t)bh * 65536;
    const f16* Vbase = VpT + (size_t)bh * 65536;

    auto stageK = [&](int buf, int j) {      // 512 chunks, one per thread
        const int r = tid >> 3, c = tid & 7;
        GLOAD_LDS16(&Kbase[(size_t)(j * 64 + r) * 64 + (c ^ (r & 7)) * 8],
                    (char*)&Ks[buf][0][0] + (size_t)tid * 16);
    };
    auto stageV = [&](int j) {
        const int r = tid >> 3, c = tid & 7;
        GLOAD_LDS16(&Vbase[(size_t)r * 1024 + j * 64 + (c ^ (r & 7)) * 8],
                    (char*)&Vs[0][0] + (size_t)tid * 16);
    };

    if (tid < 16) {
#pragma unroll
        for (int i = 0; i < 4; ++i) {
            const float on = ((tid >> i) & 1) ? 1.0f : 0.0f;
            LUTf[tid][i] = on;
            LUTh[tid][i] = (f16)on;
        }
    }
    const int rowm = w * 16 + l15;       // this thread's q-row (swapped S^T layout)
    const int swp = (rowm & 7) << 3;
    const int kb0 = t4 * 4;              // contiguous 4-k-col base
    // Q fragments: direct global -> registers (Qs LDS eliminated; read-once data)
    const f16x8 afA = *(const f16x8*)&Qbase[(size_t)(m0 + rowm) * 64 + t4 * 8];
    const f16x8 afB = *(const f16x8*)&Qbase[(size_t)(m0 + rowm) * 64 + 32 + t4 * 8];
    // per-row mask word pointer (bits is 1 MB -> L2/L3-resident, re-read per j)
    const unsigned* bmrow = &bits[((size_t)b * 1024 + m0 + rowm) * 32];

    stageK(0, 0);
    __syncthreads();

    float lsA = 0.f, lsB = 0.f;          // split accumulators (break fma chain)

    // -------- sweep 1: l = sum_col exp2(s) * mask --------
    for (int j = 0; j < 16; ++j) {
        if (j < 15) stageK((j + 1) & 1, j + 1);
        const uint2 bw = *(const uint2*)&bmrow[2 * j];   // issued early, hides under MFMA

        f32x4 acc[4];
#pragma unroll
        for (int ni = 0; ni < 4; ++ni) acc[ni] = (f32x4){0.f, 0.f, 0.f, 0.f};
#pragma unroll
        for (int ks = 0; ks < 2; ++ks) {
            const int slot = ks * 4 + t4;
            const f16x8 af = ks ? afB : afA;
#pragma unroll
            for (int ni = 0; ni < 4; ++ni) {
                const int row = ni * 16 + l15;
                const f16x8 bf = *(const f16x8*)&Ks[j & 1][row][(slot ^ (row & 7)) * 8];
                acc[ni] = __builtin_amdgcn_mfma_f32_16x16x32_f16(bf, af, acc[ni], 0, 0, 0);
            }
        }

#pragma unroll
        for (int ni = 0; ni < 4; ++ni) {
            const unsigned word = (ni >> 1) ? bw.y : bw.x;
            const unsigned nib = (word >> (((ni & 1) << 4) + kb0)) & 15u;
            const float4 mf = *(const float4*)&LUTf[nib][0];
            lsA = fmaf(exp2f(acc[ni][0]), mf.x, lsA);
            lsB = fmaf(exp2f(acc[ni][1]), mf.y, lsB);
            lsA = fmaf(exp2f(acc[ni][2]), mf.z, lsA);
            lsB = fmaf(exp2f(acc[ni][3]), mf.w, lsB);
        }
        __syncthreads();
    }

    // stage sweep-2 K tile 0 while reducing lsum
    stageK(0, 0);

    f16x2 rlp;
    {
        float s = lsA + lsB;
        s += __shfl_xor(s, 16);
        s += __shfl_xor(s, 32);
        const f16 rlh = (f16)(1.0f / s);
        rlp[0] = rlh; rlp[1] = rlh;
    }

    f32x4 accP[4];
#pragma unroll
    for (int ni = 0; ni < 4; ++ni) accP[ni] = (f32x4){0.f, 0.f, 0.f, 0.f};

    float* attnBase = attn + ((size_t)b * 1024 + m0) * 16384 + h * 1024;
    const int st_r0 = tid >> 4;       // store readback: row base (0..31)
    const int st_c4 = tid & 15;       // float4 column
    __syncthreads();

    // -------- sweep 2: recompute, normalized p -> Ps (packed); PV; store p from Ps --------
    for (int j = 0; j < 16; ++j) {
        if (j < 15) stageK((j + 1) & 1, j + 1);
        stageV(j);                    // single buffer; ready at mid-barrier
        const uint2 bw = *(const uint2*)&bmrow[2 * j];

        f32x4 acc[4];
#pragma unroll
        for (int ni = 0; ni < 4; ++ni) acc[ni] = (f32x4){0.f, 0.f, 0.f, 0.f};
#pragma unroll
        for (int ks = 0; ks < 2; ++ks) {
            const int slot = ks * 4 + t4;
            const f16x8 af = ks ? afB : afA;
#pragma unroll
            for (int ni = 0; ni < 4; ++ni) {
                const int row = ni * 16 + l15;
                const f16x8 bf = *(const f16x8*)&Ks[j & 1][row][(slot ^ (row & 7)) * 8];
                acc[ni] = __builtin_amdgcn_mfma_f32_16x16x32_f16(bf, af, acc[ni], 0, 0, 0);
            }
        }

#pragma unroll
        for (int ni = 0; ni < 4; ++ni) {
            const unsigned word = (ni >> 1) ? bw.y : bw.x;
            const unsigned nib = (word >> (((ni & 1) << 4) + kb0)) & 15u;
            const f16x4 mh = *(const f16x4*)&LUTh[nib][0];
            f16x2 p01 = cvt_pk_f16(exp2f(acc[ni][0]), exp2f(acc[ni][1]));
            f16x2 p23 = cvt_pk_f16(exp2f(acc[ni][2]), exp2f(acc[ni][3]));
            p01 = p01 * (f16x2){mh[0], mh[1]} * rlp;
            p23 = p23 * (f16x2){mh[2], mh[3]} * rlp;
            f16x4 pw; pw[0] = p01[0]; pw[1] = p01[1]; pw[2] = p23[0]; pw[3] = p23[1];
            *(f16x4*)&Ps[rowm][(ni * 16 + kb0) ^ swp] = pw;
        }
        __syncthreads();   // Ps visible; Vs(j) drained

        // PV MFMA (normalized P)
#pragma unroll
        for (int ks = 0; ks < 2; ++ks) {
            const int slot = ks * 4 + t4;
            const f16x8 pf = *(const f16x8*)&Ps[rowm][(slot ^ (rowm & 7)) * 8];
#pragma unroll
            for (int ni = 0; ni < 4; ++ni) {
                const int row = ni * 16 + l15;
                const f16x8 vf = *(const f16x8*)&Vs[row][(slot ^ (row & 7)) * 8];
                accP[ni] = __builtin_amdgcn_mfma_f32_16x16x32_f16(pf, vf, accP[ni], 0, 0, 0);
            }
        }

        // coalesced p store from Ps (256B per 16 lanes), overlaps MFMA
#pragma unroll
        for (int i = 0; i < 4; ++i) {
            const int row = st_r0 + 32 * i;
            const f16x4 hv = *(const f16x4*)((const char*)&Ps[row][0] +
                    ((st_c4 >> 1) ^ (row & 7)) * 16 + (st_c4 & 1) * 8);
            f32x4 fv = {(float)hv[0], (float)hv[1], (float)hv[2], (float)hv[3]};
            __builtin_nontemporal_store(fv,
                    (f32x4*)&attnBase[(size_t)row * 16384 + j * 64 + st_c4 * 4]);
        }
        __syncthreads();
    }

#pragma unroll
    for (int ni = 0; ni < 4; ++ni) {
        const int row0 = m0 + w * 16 + (t4 << 2);
        const int col = ni * 16 + l15;
#pragma unroll
        for (int r = 0; r < 4; ++r)
            headcat[((size_t)b * 1024 + row0 + r) * 1024 + h * 64 + col] = (f16)accP[ni][r];
    }
}

extern "C" void kernel_launch(void* const* d_in, const int* in_sizes, int n_in,
                              void* d_out, int out_size, void* d_ws, size_t ws_size,
                              hipStream_t stream) {
    const float* q = (const float*)d_in[0];
    const float* k = (const float*)d_in[1];
    const float* v = (const float*)d_in[2];
    const int* mask = (const int*)d_in[3];
    const float* Wq = (const float*)d_in[4];
    const float* Wk = (const float*)d_in[5];
    const float* Wv = (const float*)d_in[6];
    const float* Wo = (const float*)d_in[7];
    const float* bo = (const float*)d_in[8];

    float* out0 = (float*)d_out;                  // [8,1024,1024]
    float* attn = out0 + (size_t)8 * 1024 * 1024; // [8,1024,16384]

    char* ws = (char*)d_ws;
    f16* wt   = (f16*)(ws + ((size_t)0 << 20));   // wqt,wkt,wvt,wot contiguous: 8 MiB
    f16* qh   = (f16*)(ws + ((size_t)8 << 20));   // q,k,v f16 contiguous: 48 MiB
    f16* Qp   = (f16*)(ws + ((size_t)56 << 20));  // Qp,Kp,VpT contiguous: 48 MiB
    f16* Kp   = (f16*)(ws + ((size_t)72 << 20));
    f16* VpT  = (f16*)(ws + ((size_t)88 << 20));
    f16* hc   = (f16*)(ws + ((size_t)104 << 20)); // [B*L, 1024] f16
    unsigned* bits = (unsigned*)(ws + ((size_t)120 << 20)); // 1 MiB bitmask
    f16* wot  = wt + (size_t)3 * 1048576;

    prep_kernel<<<13312, 256, 0, stream>>>(q, k, v, Wq, Wk, Wv, Wo, qh, wt);

    proj_kernel<<<2560, 256, 0, stream>>>(qh, wt, Qp, mask, bits);

    attn_fused_kernel<<<1024, 512, 0, stream>>>(Qp, Kp, VpT, bits, attn, hc);

    out_kernel<<<512, 256, 0, stream>>>(hc, wot, out0, bo);
}

// Round 16
// 277.616 us; speedup vs baseline: 1.0401x; 1.0401x over previous
//
#include <hip/hip_runtime.h>

typedef _Float16 f16;
typedef _Float16 f16x8 __attribute__((ext_vector_type(8)));
typedef _Float16 f16x4 __attribute__((ext_vector_type(4)));
typedef _Float16 f16x2 __attribute__((ext_vector_type(2)));
typedef float f32x4 __attribute__((ext_vector_type(4)));
typedef int i32x4 __attribute__((ext_vector_type(4)));

#define GLOAD_LDS16(g, l) \
    __builtin_amdgcn_global_load_lds((const __attribute__((address_space(1))) void*)(g), \
                                     (__attribute__((address_space(3))) void*)(l), 16, 0, 0)

__device__ __forceinline__ f16x2 cvt_pk_f16(float a, float b) {
    return __builtin_bit_cast(f16x2, __builtin_amdgcn_cvt_pkrtz(a, b));
}

// 0.125 * log2(e): Qp is pre-scaled by this so attn uses exp2(acc) directly
#define SC_LOG2E 0.180336880f

// ---------------- merged prep (no maskbits — that overlaps with proj) ----------------
// bid<12288: q/k/v cvt | <13056: Wq/Wk/Wv LDS-transpose | <13312: Wo LDS-transpose
__global__ __launch_bounds__(256) void prep_kernel(const float* __restrict__ q,
        const float* __restrict__ k, const float* __restrict__ v,
        const float* __restrict__ Wq, const float* __restrict__ Wk,
        const float* __restrict__ Wv, const float* __restrict__ Wo,
        f16* __restrict__ qh, f16* __restrict__ wt) {
    __shared__ float tile[64][68];
    const int bid = blockIdx.x;
    const int tid = threadIdx.x;
    if (bid < 12288) {
        const int z = bid >> 12;
        const float* src = (z == 0) ? q : (z == 1) ? k : v;
        const size_t i = ((size_t)(bid & 4095) * 256 + tid) * 8;
        float4 a = *(const float4*)&src[i], b2 = *(const float4*)&src[i + 4];
        f16x8 h;
        h[0] = (f16)a.x; h[1] = (f16)a.y; h[2] = (f16)a.z; h[3] = (f16)a.w;
        h[4] = (f16)b2.x; h[5] = (f16)b2.y; h[6] = (f16)b2.z; h[7] = (f16)b2.w;
        *(f16x8*)&qh[(size_t)z * 8388608 + i] = h;
    } else if (bid < 13056) {
        // Wq/Wk/Wv: [h, d, kk] -> wt[z][n=h*64+kk][d], 64x64 tile over (d, kk)
        const int t2 = bid - 12288;
        const int z = t2 >> 8;
        const int rem = t2 & 255;
        const int h = rem >> 4, d0 = (rem & 15) * 64;
        const float* W = (z == 0) ? Wq : (z == 1) ? Wk : Wv;
        const int rr = tid >> 4, c4 = (tid & 15) * 4;
#pragma unroll
        for (int i = 0; i < 4; ++i) {
            const int dd = rr + 16 * i;
            *(float4*)&tile[dd][c4] = *(const float4*)&W[((size_t)h * 1024 + d0 + dd) * 64 + c4];
        }
        __syncthreads();
#pragma unroll
        for (int i = 0; i < 4; ++i) {
            const int kk = rr + 16 * i;
            f16x4 hv;
            hv[0] = (f16)tile[c4 + 0][kk];
            hv[1] = (f16)tile[c4 + 1][kk];
            hv[2] = (f16)tile[c4 + 2][kk];
            hv[3] = (f16)tile[c4 + 3][kk];
            *(f16x4*)&wt[(size_t)z * 1048576 + (size_t)(h * 64 + kk) * 1024 + d0 + c4] = hv;
        }
    } else {
        // Wo: [d][n] -> wt[3][n][d], 64x64 tile over (d, n)
        const int rem = bid - 13056;
        const int d0 = (rem >> 4) * 64, n0 = (rem & 15) * 64;
        const int rr = tid >> 4, c4 = (tid & 15) * 4;
#pragma unroll
        for (int i = 0; i < 4; ++i) {
            const int dd = rr + 16 * i;
            *(float4*)&tile[dd][c4] = *(const float4*)&Wo[(size_t)(d0 + dd) * 1024 + n0 + c4];
        }
        __syncthreads();
#pragma unroll
        for (int i = 0; i < 4; ++i) {
            const int nn = rr + 16 * i;
            f16x4 hv;
            hv[0] = (f16)tile[c4 + 0][nn];
            hv[1] = (f16)tile[c4 + 1][nn];
            hv[2] = (f16)tile[c4 + 2][nn];
            hv[3] = (f16)tile[c4 + 3][nn];
            *(f16x4*)&wt[(size_t)3 * 1048576 + (size_t)(n0 + nn) * 1024 + d0 + c4] = hv;
        }
    }
}

// ---------------- fused Q/K/V projection GEMM + overlapped maskbits -----------------
__global__ __launch_bounds__(256) void proj_kernel(const f16* __restrict__ Ah,
        const f16* __restrict__ Wt, f16* __restrict__ Outp,
        const int* __restrict__ mask, unsigned* __restrict__ bits) {
    __shared__ __align__(16) f16 As[128][64];
    __shared__ __align__(16) f16 Bs[128][64];
    const int id = blockIdx.x;
    const int tid = threadIdx.x;
    if (id >= 1536) {
        const int t = (id - 1536) * 256 + tid;
        const i32x4* src = (const i32x4*)mask + (size_t)t * 8;
        unsigned w = 0;
#pragma unroll
        for (int i = 0; i < 8; ++i) {
            i32x4 vv = __builtin_nontemporal_load(src + i);   // don't evict qh/Qp from L2/L3
            w |= (vv.x != 0 ? 1u : 0u) << (i * 4 + 0);
            w |= (vv.y != 0 ? 1u : 0u) << (i * 4 + 1);
            w |= (vv.z != 0 ? 1u : 0u) << (i * 4 + 2);
            w |= (vv.w != 0 ? 1u : 0u) << (i * 4 + 3);
        }
        bits[t] = w;
        return;
    }
    const int z = id >> 9;
    const int id2 = id & 511;
    const int m0 = ((id2 & 7) * 8 + ((id2 >> 3) & 7)) * 128;
    const int n0 = (id2 >> 6) * 128;
    const f16* A = Ah + (size_t)z * 8388608;
    const f16* Bt = Wt + (size_t)z * 1048576;
    f16* Out = Outp + (size_t)z * 8388608;
    const int lane = tid & 63;
    const int w = tid >> 6, wr = w >> 1, wc = w & 1;

    f32x4 acc[4][4];
#pragma unroll
    for (int mi = 0; mi < 4; ++mi)
#pragma unroll
        for (int ni = 0; ni < 4; ++ni) acc[mi][ni] = (f32x4){0.f, 0.f, 0.f, 0.f};

    for (int kt = 0; kt < 16; ++kt) {
        const int k0 = kt * 64;
#pragma unroll
        for (int seg = 0; seg < 4; ++seg) {
            const int ch = seg * 256 + tid, r = ch >> 3, c = ch & 7;
            GLOAD_LDS16(&A[(size_t)(m0 + r) * 1024 + k0 + (c ^ (r & 7)) * 8],
                        (char*)&As[0][0] + (seg * 256 + w * 64) * 16);
            GLOAD_LDS16(&Bt[(size_t)(n0 + r) * 1024 + k0 + (c ^ (r & 7)) * 8],
                        (char*)&Bs[0][0] + (seg * 256 + w * 64) * 16);
        }
        __syncthreads();
#pragma unroll
        for (int ks = 0; ks < 2; ++ks) {
            const int slot = ks * 4 + (lane >> 4);
            f16x8 af[4], bf[4];
#pragma unroll
            for (int mi = 0; mi < 4; ++mi) {
                const int row = wr * 64 + mi * 16 + (lane & 15);
                af[mi] = *(const f16x8*)&As[row][(slot ^ (row & 7)) * 8];
            }
#pragma unroll
            for (int ni = 0; ni < 4; ++ni) {
                const int row = wc * 64 + ni * 16 + (lane & 15);
                bf[ni] = *(const f16x8*)&Bs[row][(slot ^ (row & 7)) * 8];
            }
#pragma unroll
            for (int mi = 0; mi < 4; ++mi)
#pragma unroll
                for (int ni = 0; ni < 4; ++ni)
                    acc[mi][ni] = __builtin_amdgcn_mfma_f32_16x16x32_f16(af[mi], bf[ni], acc[mi][ni], 0, 0, 0);
        }
        __syncthreads();
    }

    const float sc = (z == 0) ? SC_LOG2E : 1.0f;
#pragma unroll
    for (int mi = 0; mi < 4; ++mi)
#pragma unroll
        for (int ni = 0; ni < 4; ++ni) {
            const int row0 = m0 + wr * 64 + mi * 16 + ((lane >> 4) << 2);
            const int col = n0 + wc * 64 + ni * 16 + (lane & 15);
            const int h = col >> 6, kk = col & 63;
            const int b = row0 >> 10, l0 = row0 & 1023;
            if (z < 2) {
#pragma unroll
                for (int r = 0; r < 4; ++r)
                    Out[(((size_t)(b * 16 + h) * 1024) + l0 + r) * 64 + kk] = (f16)(acc[mi][ni][r] * sc);
            } else {
                f16x4 hv;
#pragma unroll
                for (int r = 0; r < 4; ++r) hv[r] = (f16)acc[mi][ni][r];
                *(f16x4*)&Out[((size_t)(b * 16 + h) * 64 + kk) * 1024 + l0] = hv;
            }
        }
}

// ---------------- output projection GEMM: out0 = hc @ Wo^T + bo (f32, nt stores) --------
__global__ __launch_bounds__(256) void out_kernel(const f16* __restrict__ A,
        const f16* __restrict__ Bt, float* __restrict__ O, const float* __restrict__ bias) {
    __shared__ __align__(16) f16 As[128][64];
    __shared__ __align__(16) f16 Bs[128][64];
    const int id2 = blockIdx.x;
    const int m0 = ((id2 & 7) * 8 + ((id2 >> 3) & 7)) * 128;
    const int n0 = (id2 >> 6) * 128;
    const int tid = threadIdx.x, lane = tid & 63;
    const int w = tid >> 6, wr = w >> 1, wc = w & 1;

    f32x4 acc[4][4];
#pragma unroll
    for (int mi = 0; mi < 4; ++mi)
#pragma unroll
        for (int ni = 0; ni < 4; ++ni) acc[mi][ni] = (f32x4){0.f, 0.f, 0.f, 0.f};

    for (int kt = 0; kt < 16; ++kt) {
        const int k0 = kt * 64;
#pragma unroll
        for (int seg = 0; seg < 4; ++seg) {
            const int ch = seg * 256 + tid, r = ch >> 3, c = ch & 7;
            GLOAD_LDS16(&A[(size_t)(m0 + r) * 1024 + k0 + (c ^ (r & 7)) * 8],
                        (char*)&As[0][0] + (seg * 256 + w * 64) * 16);
            GLOAD_LDS16(&Bt[(size_t)(n0 + r) * 1024 + k0 + (c ^ (r & 7)) * 8],
                        (char*)&Bs[0][0] + (seg * 256 + w * 64) * 16);
        }
        __syncthreads();
#pragma unroll
        for (int ks = 0; ks < 2; ++ks) {
            const int slot = ks * 4 + (lane >> 4);
            f16x8 af[4], bf[4];
#pragma unroll
            for (int mi = 0; mi < 4; ++mi) {
                const int row = wr * 64 + mi * 16 + (lane & 15);
                af[mi] = *(const f16x8*)&As[row][(slot ^ (row & 7)) * 8];
            }
#pragma unroll
            for (int ni = 0; ni < 4; ++ni) {
                const int row = wc * 64 + ni * 16 + (lane & 15);
                bf[ni] = *(const f16x8*)&Bs[row][(slot ^ (row & 7)) * 8];
            }
#pragma unroll
            for (int mi = 0; mi < 4; ++mi)
#pragma unroll
                for (int ni = 0; ni < 4; ++ni)
                    acc[mi][ni] = __builtin_amdgcn_mfma_f32_16x16x32_f16(af[mi], bf[ni], acc[mi][ni], 0, 0, 0);
        }
        __syncthreads();
    }

#pragma unroll
    for (int mi = 0; mi < 4; ++mi)
#pragma unroll
        for (int ni = 0; ni < 4; ++ni) {
            const int row0 = m0 + wr * 64 + mi * 16 + ((lane >> 4) << 2);
            const int col = n0 + wc * 64 + ni * 16 + (lane & 15);
            const float bb = bias[col];
#pragma unroll
            for (int r = 0; r < 4; ++r)
                __builtin_nontemporal_store(acc[mi][ni][r] + bb, &O[(size_t)(row0 + r) * 1024 + col]);
        }
}

// ---------------- fused attention: 512 threads, no Qs LDS (Q direct->reg), bm in LDS ----
// LDS = Ks 32K + Vs 8K + Ps 16K + bm 16K + LUT ~0.3K = 72.3K -> 2 blocks/CU (16 waves/CU)
__global__ __launch_bounds__(512, 4) void attn_fused_kernel(const f16* __restrict__ Qp,
        const f16* __restrict__ Kp, const f16* __restrict__ VpT,
        const unsigned* __restrict__ bits, float* __restrict__ attn, f16* __restrict__ headcat) {
    __shared__ __align__(16) f16 Ks[2][64][64];
    __shared__ __align__(16) f16 Vs[64][64];          // single buffer
    __shared__ __align__(16) f16 Ps[128][64];
    __shared__ unsigned bm[128][32];                  // word w stored at w ^ ((row&7)<<2)
    __shared__ __align__(16) float LUTf[16][4];
    __shared__ __align__(16) f16 LUTh[16][4];
    const int bh = blockIdx.x & 127, m0 = (blockIdx.x >> 7) * 128;
    const int b = bh >> 4, h = bh & 15;
    const int tid = threadIdx.x, lane = tid & 63, w = tid >> 6;  // w in [0,8)
    const int l15 = lane & 15, t4 = lane >> 4;
    const f16* Qbase = Qp + (size_t)bh * 65536;
    const f16* Kbase = Kp + (size_t)bh * 65536;
    const f16* Vbase = VpT + (size_t)bh * 65536;

    auto stageK = [&](int buf, int j) {      // 512 chunks, one per thread
        const int r = tid >> 3, c = tid & 7;
        GLOAD_LDS16(&Kbase[(size_t)(j * 64 + r) * 64 + (c ^ (r & 7)) * 8],
                    (char*)&Ks[buf][0][0] + (size_t)tid * 16);
    };
    auto stageV = [&](int j) {
        const int r = tid >> 3, c = tid & 7;
        GLOAD_LDS16(&Vbase[(size_t)r * 1024 + j * 64 + (c ^ (r & 7)) * 8],
                    (char*)&Vs[0][0] + (size_t)tid * 16);
    };

    if (tid < 16) {
#pragma unroll
        for (int i = 0; i < 4; ++i) {
            const float on = ((tid >> i) & 1) ? 1.0f : 0.0f;
            LUTf[tid][i] = on;
            LUTh[tid][i] = (f16)on;
        }
    }
    // prologue: bm (16 KB, word-swizzled) + K tile 0; Q frags direct global->reg
#pragma unroll
    for (int seg = 0; seg < 2; ++seg) {
        const int ch = seg * 512 + tid, r = ch >> 3, c = ch & 7;
        GLOAD_LDS16((const char*)&bits[((size_t)b * 1024 + m0 + r) * 32] + (c ^ (r & 7)) * 16,
                    (char*)&bm[0][0] + (size_t)ch * 16);
    }
    stageK(0, 0);

    const int rowm = w * 16 + l15;       // this thread's q-row (swapped S^T layout)
    const int swb = (rowm & 7) << 2;
    const int swp = (rowm & 7) << 3;
    const int kb0 = t4 * 4;              // contiguous 4-k-col base
    // Q fragments: direct global -> registers (read-once; Qs LDS eliminated)
    const f16x8 afA = *(const f16x8*)&Qbase[(size_t)(m0 + rowm) * 64 + t4 * 8];
    const f16x8 afB = *(const f16x8*)&Qbase[(size_t)(m0 + rowm) * 64 + 32 + t4 * 8];
    __syncthreads();

    float lsA = 0.f, lsB = 0.f;          // split accumulators (break fma chain)

    // -------- sweep 1: l = sum_col exp2(s) * mask --------
    for (int j = 0; j < 16; ++j) {
        if (j < 15) stageK((j + 1) & 1, j + 1);

        f32x4 acc[4];
#pragma unroll
        for (int ni = 0; ni < 4; ++ni) acc[ni] = (f32x4){0.f, 0.f, 0.f, 0.f};
#pragma unroll
        for (int ks = 0; ks < 2; ++ks) {
            const int slot = ks * 4 + t4;
            const f16x8 af = ks ? afB : afA;
#pragma unroll
            for (int ni = 0; ni < 4; ++ni) {
                const int row = ni * 16 + l15;
                const f16x8 bf = *(const f16x8*)&Ks[j & 1][row][(slot ^ (row & 7)) * 8];
                acc[ni] = __builtin_amdgcn_mfma_f32_16x16x32_f16(bf, af, acc[ni], 0, 0, 0);
            }
        }

#pragma unroll
        for (int ni = 0; ni < 4; ++ni) {
            const unsigned word = bm[rowm][(2 * j + (ni >> 1)) ^ swb];
            const unsigned nib = (word >> (((ni & 1) << 4) + kb0)) & 15u;
            const float4 mf = *(const float4*)&LUTf[nib][0];
            lsA = fmaf(exp2f(acc[ni][0]), mf.x, lsA);
            lsB = fmaf(exp2f(acc[ni][1]), mf.y, lsB);
            lsA = fmaf(exp2f(acc[ni][2]), mf.z, lsA);
            lsB = fmaf(exp2f(acc[ni][3]), mf.w, lsB);
        }
        __syncthreads();
    }

    // stage sweep-2 K tile 0 while reducing lsum
    stageK(0, 0);

    f16x2 rlp;
    {
        float s = lsA + lsB;
        s += __shfl_xor(s, 16);
        s += __shfl_xor(s, 32);
        const f16 rlh = (f16)(1.0f / s);
        rlp[0] = rlh; rlp[1] = rlh;
    }

    f32x4 accP[4];
#pragma unroll
    for (int ni = 0; ni < 4; ++ni) accP[ni] = (f32x4){0.f, 0.f, 0.f, 0.f};

    float* attnBase = attn + ((size_t)b * 1024 + m0) * 16384 + h * 1024;
    const int st_r0 = tid >> 4;       // store readback: row base (0..31)
    const int st_c4 = tid & 15;       // float4 column
    __syncthreads();

    // -------- sweep 2: recompute, normalized p -> Ps (packed); PV; store p from Ps --------
    for (int j = 0; j < 16; ++j) {
        if (j < 15) stageK((j + 1) & 1, j + 1);
        stageV(j);                    // single buffer; ready at mid-barrier

        f32x4 acc[4];
#pragma unroll
        for (int ni = 0; ni < 4; ++ni) acc[ni] = (f32x4){0.f, 0.f, 0.f, 0.f};
#pragma unroll
        for (int ks = 0; ks < 2; ++ks) {
            const int slot = ks * 4 + t4;
            const f16x8 af = ks ? afB : afA;
#pragma unroll
            for (int ni = 0; ni < 4; ++ni) {
                const int row = ni * 16 + l15;
                const f16x8 bf = *(const f16x8*)&Ks[j & 1][row][(slot ^ (row & 7)) * 8];
                acc[ni] = __builtin_amdgcn_mfma_f32_16x16x32_f16(bf, af, acc[ni], 0, 0, 0);
            }
        }

#pragma unroll
        for (int ni = 0; ni < 4; ++ni) {
            const unsigned word = bm[rowm][(2 * j + (ni >> 1)) ^ swb];
            const unsigned nib = (word >> (((ni & 1) << 4) + kb0)) & 15u;
            const f16x4 mh = *(const f16x4*)&LUTh[nib][0];
            f16x2 p01 = cvt_pk_f16(exp2f(acc[ni][0]), exp2f(acc[ni][1]));
            f16x2 p23 = cvt_pk_f16(exp2f(acc[ni][2]), exp2f(acc[ni][3]));
            p01 = p01 * (f16x2){mh[0], mh[1]} * rlp;
            p23 = p23 * (f16x2){mh[2], mh[3]} * rlp;
            f16x4 pw; pw[0] = p01[0]; pw[1] = p01[1]; pw[2] = p23[0]; pw[3] = p23[1];
            *(f16x4*)&Ps[rowm][(ni * 16 + kb0) ^ swp] = pw;
        }
        __syncthreads();   // Ps visible; Vs(j) drained

        // PV MFMA (normalized P)
#pragma unroll
        for (int ks = 0; ks < 2; ++ks) {
            const int slot = ks * 4 + t4;
            const f16x8 pf = *(const f16x8*)&Ps[rowm][(slot ^ (rowm & 7)) * 8];
#pragma unroll
            for (int ni = 0; ni < 4; ++ni) {
                const int row = ni * 16 + l15;
                const f16x8 vf = *(const f16x8*)&Vs[row][(slot ^ (row & 7)) * 8];
                accP[ni] = __builtin_amdgcn_mfma_f32_16x16x32_f16(pf, vf, accP[ni], 0, 0, 0);
            }
        }

        // coalesced p store from Ps (256B per 16 lanes), overlaps MFMA
#pragma unroll
        for (int i = 0; i < 4; ++i) {
            const int row = st_r0 + 32 * i;
            const f16x4 hv = *(const f16x4*)((const char*)&Ps[row][0] +
                    ((st_c4 >> 1) ^ (row & 7)) * 16 + (st_c4 & 1) * 8);
            f32x4 fv = {(float)hv[0], (float)hv[1], (float)hv[2], (float)hv[3]};
            __builtin_nontemporal_store(fv,
                    (f32x4*)&attnBase[(size_t)row * 16384 + j * 64 + st_c4 * 4]);
        }
        __syncthreads();
    }

#pragma unroll
    for (int ni = 0; ni < 4; ++ni) {
        const int row0 = m0 + w * 16 + (t4 << 2);
        const int col = ni * 16 + l15;
#pragma unroll
        for (int r = 0; r < 4; ++r)
            headcat[((size_t)b * 1024 + row0 + r) * 1024 + h * 64 + col] = (f16)accP[ni][r];
    }
}

extern "C" void kernel_launch(void* const* d_in, const int* in_sizes, int n_in,
                              void* d_out, int out_size, void* d_ws, size_t ws_size,
                              hipStream_t stream) {
    const float* q = (const float*)d_in[0];
    const float* k = (const float*)d_in[1];
    const float* v = (const float*)d_in[2];
    const int* mask = (const int*)d_in[3];
    const float* Wq = (const float*)d_in[4];
    const float* Wk = (const float*)d_in[5];
    const float* Wv = (const float*)d_in[6];
    const float* Wo = (const float*)d_in[7];
    const float* bo = (const float*)d_in[8];

    float* out0 = (float*)d_out;                  // [8,1024,1024]
    float* attn = out0 + (size_t)8 * 1024 * 1024; // [8,1024,16384]

    char* ws = (char*)d_ws;
    f16* wt   = (f16*)(ws + ((size_t)0 << 20));   // wqt,wkt,wvt,wot contiguous: 8 MiB
    f16* qh   = (f16*)(ws + ((size_t)8 << 20));   // q,k,v f16 contiguous: 48 MiB
    f16* Qp   = (f16*)(ws + ((size_t)56 << 20));  // Qp,Kp,VpT contiguous: 48 MiB
    f16* Kp   = (f16*)(ws + ((size_t)72 << 20));
    f16* VpT  = (f16*)(ws + ((size_t)88 << 20));
    f16* hc   = (f16*)(ws + ((size_t)104 << 20)); // [B*L, 1024] f16
    unsigned* bits = (unsigned*)(ws + ((size_t)120 << 20)); // 1 MiB bitmask
    f16* wot  = wt + (size_t)3 * 1048576;

    prep_kernel<<<13312, 256, 0, stream>>>(q, k, v, Wq, Wk, Wv, Wo, qh, wt);

    proj_kernel<<<2560, 256, 0, stream>>>(qh, wt, Qp, mask, bits);

    attn_fused_kernel<<<1024, 512, 0, stream>>>(Qp, Kp, VpT, bits, attn, hc);

    out_kernel<<<512, 256, 0, stream>>>(hc, wot, out0, bo);
}

// Round 17
// 270.058 us; speedup vs baseline: 1.0692x; 1.0280x over previous
//
#include <hip/hip_runtime.h>

typedef _Float16 f16;
typedef _Float16 f16x8 __attribute__((ext_vector_type(8)));
typedef _Float16 f16x4 __attribute__((ext_vector_type(4)));
typedef _Float16 f16x2 __attribute__((ext_vector_type(2)));
typedef float f32x4 __attribute__((ext_vector_type(4)));

#define GLOAD_LDS16(g, l) \
    __builtin_amdgcn_global_load_lds((const __attribute__((address_space(1))) void*)(g), \
                                     (__attribute__((address_space(3))) void*)(l), 16, 0, 0)

__device__ __forceinline__ f16x2 cvt_pk_f16(float a, float b) {
    return __builtin_bit_cast(f16x2, __builtin_amdgcn_cvt_pkrtz(a, b));
}

// 0.125 * log2(e): Qp is pre-scaled by this so attn uses exp2(acc) directly
#define SC_LOG2E 0.180336880f

// ---------------- merged prep (no maskbits — that overlaps with proj) ----------------
// bid<12288: q/k/v cvt | <13056: Wq/Wk/Wv LDS-transpose | <13312: Wo LDS-transpose
__global__ __launch_bounds__(256) void prep_kernel(const float* __restrict__ q,
        const float* __restrict__ k, const float* __restrict__ v,
        const float* __restrict__ Wq, const float* __restrict__ Wk,
        const float* __restrict__ Wv, const float* __restrict__ Wo,
        f16* __restrict__ qh, f16* __restrict__ wt) {
    __shared__ float tile[64][68];
    const int bid = blockIdx.x;
    const int tid = threadIdx.x;
    if (bid < 12288) {
        const int z = bid >> 12;
        const float* src = (z == 0) ? q : (z == 1) ? k : v;
        const size_t i = ((size_t)(bid & 4095) * 256 + tid) * 8;
        float4 a = *(const float4*)&src[i], b2 = *(const float4*)&src[i + 4];
        f16x8 h;
        h[0] = (f16)a.x; h[1] = (f16)a.y; h[2] = (f16)a.z; h[3] = (f16)a.w;
        h[4] = (f16)b2.x; h[5] = (f16)b2.y; h[6] = (f16)b2.z; h[7] = (f16)b2.w;
        *(f16x8*)&qh[(size_t)z * 8388608 + i] = h;
    } else if (bid < 13056) {
        // Wq/Wk/Wv: [h, d, kk] -> wt[z][n=h*64+kk][d], 64x64 tile over (d, kk)
        const int t2 = bid - 12288;
        const int z = t2 >> 8;
        const int rem = t2 & 255;
        const int h = rem >> 4, d0 = (rem & 15) * 64;
        const float* W = (z == 0) ? Wq : (z == 1) ? Wk : Wv;
        const int rr = tid >> 4, c4 = (tid & 15) * 4;
#pragma unroll
        for (int i = 0; i < 4; ++i) {
            const int dd = rr + 16 * i;
            *(float4*)&tile[dd][c4] = *(const float4*)&W[((size_t)h * 1024 + d0 + dd) * 64 + c4];
        }
        __syncthreads();
#pragma unroll
        for (int i = 0; i < 4; ++i) {
            const int kk = rr + 16 * i;
            f16x4 hv;
            hv[0] = (f16)tile[c4 + 0][kk];
            hv[1] = (f16)tile[c4 + 1][kk];
            hv[2] = (f16)tile[c4 + 2][kk];
            hv[3] = (f16)tile[c4 + 3][kk];
            *(f16x4*)&wt[(size_t)z * 1048576 + (size_t)(h * 64 + kk) * 1024 + d0 + c4] = hv;
        }
    } else {
        // Wo: [d][n] -> wt[3][n][d], 64x64 tile over (d, n)
        const int rem = bid - 13056;
        const int d0 = (rem >> 4) * 64, n0 = (rem & 15) * 64;
        const int rr = tid >> 4, c4 = (tid & 15) * 4;
#pragma unroll
        for (int i = 0; i < 4; ++i) {
            const int dd = rr + 16 * i;
            *(float4*)&tile[dd][c4] = *(const float4*)&Wo[(size_t)(d0 + dd) * 1024 + n0 + c4];
        }
        __syncthreads();
#pragma unroll
        for (int i = 0; i < 4; ++i) {
            const int nn = rr + 16 * i;
            f16x4 hv;
            hv[0] = (f16)tile[c4 + 0][nn];
            hv[1] = (f16)tile[c4 + 1][nn];
            hv[2] = (f16)tile[c4 + 2][nn];
            hv[3] = (f16)tile[c4 + 3][nn];
            *(f16x4*)&wt[(size_t)3 * 1048576 + (size_t)(n0 + nn) * 1024 + d0 + c4] = hv;
        }
    }
}

// ---------------- fused Q/K/V projection GEMM + overlapped maskbits -----------------
// blocks 0..1535: GEMM (z = id>>9); blocks 1536..2559: maskbits (memory-bound, rides
// under the GEMM's MFMA pipeline — bits are only consumed by the later attn launch)
__global__ __launch_bounds__(256) void proj_kernel(const f16* __restrict__ Ah,
        const f16* __restrict__ Wt, f16* __restrict__ Outp,
        const int* __restrict__ mask, unsigned* __restrict__ bits) {
    __shared__ __align__(16) f16 As[128][64];
    __shared__ __align__(16) f16 Bs[128][64];
    const int id = blockIdx.x;
    const int tid = threadIdx.x;
    if (id >= 1536) {
        const int t = (id - 1536) * 256 + tid;
        const int4* src = (const int4*)mask + (size_t)t * 8;
        unsigned w = 0;
#pragma unroll
        for (int i = 0; i < 8; ++i) {
            int4 vv = src[i];
            w |= (vv.x != 0 ? 1u : 0u) << (i * 4 + 0);
            w |= (vv.y != 0 ? 1u : 0u) << (i * 4 + 1);
            w |= (vv.z != 0 ? 1u : 0u) << (i * 4 + 2);
            w |= (vv.w != 0 ? 1u : 0u) << (i * 4 + 3);
        }
        bits[t] = w;
        return;
    }
    const int z = id >> 9;
    const int id2 = id & 511;
    const int m0 = ((id2 & 7) * 8 + ((id2 >> 3) & 7)) * 128;
    const int n0 = (id2 >> 6) * 128;
    const f16* A = Ah + (size_t)z * 8388608;
    const f16* Bt = Wt + (size_t)z * 1048576;
    f16* Out = Outp + (size_t)z * 8388608;
    const int lane = tid & 63;
    const int w = tid >> 6, wr = w >> 1, wc = w & 1;

    f32x4 acc[4][4];
#pragma unroll
    for (int mi = 0; mi < 4; ++mi)
#pragma unroll
        for (int ni = 0; ni < 4; ++ni) acc[mi][ni] = (f32x4){0.f, 0.f, 0.f, 0.f};

    for (int kt = 0; kt < 16; ++kt) {
        const int k0 = kt * 64;
#pragma unroll
        for (int seg = 0; seg < 4; ++seg) {
            const int ch = seg * 256 + tid, r = ch >> 3, c = ch & 7;
            GLOAD_LDS16(&A[(size_t)(m0 + r) * 1024 + k0 + (c ^ (r & 7)) * 8],
                        (char*)&As[0][0] + (seg * 256 + w * 64) * 16);
            GLOAD_LDS16(&Bt[(size_t)(n0 + r) * 1024 + k0 + (c ^ (r & 7)) * 8],
                        (char*)&Bs[0][0] + (seg * 256 + w * 64) * 16);
        }
        __syncthreads();
#pragma unroll
        for (int ks = 0; ks < 2; ++ks) {
            const int slot = ks * 4 + (lane >> 4);
            f16x8 af[4], bf[4];
#pragma unroll
            for (int mi = 0; mi < 4; ++mi) {
                const int row = wr * 64 + mi * 16 + (lane & 15);
                af[mi] = *(const f16x8*)&As[row][(slot ^ (row & 7)) * 8];
            }
#pragma unroll
            for (int ni = 0; ni < 4; ++ni) {
                const int row = wc * 64 + ni * 16 + (lane & 15);
                bf[ni] = *(const f16x8*)&Bs[row][(slot ^ (row & 7)) * 8];
            }
#pragma unroll
            for (int mi = 0; mi < 4; ++mi)
#pragma unroll
                for (int ni = 0; ni < 4; ++ni)
                    acc[mi][ni] = __builtin_amdgcn_mfma_f32_16x16x32_f16(af[mi], bf[ni], acc[mi][ni], 0, 0, 0);
        }
        __syncthreads();
    }

    const float sc = (z == 0) ? SC_LOG2E : 1.0f;
#pragma unroll
    for (int mi = 0; mi < 4; ++mi)
#pragma unroll
        for (int ni = 0; ni < 4; ++ni) {
            const int row0 = m0 + wr * 64 + mi * 16 + ((lane >> 4) << 2);
            const int col = n0 + wc * 64 + ni * 16 + (lane & 15);
            const int h = col >> 6, kk = col & 63;
            const int b = row0 >> 10, l0 = row0 & 1023;
            if (z < 2) {
#pragma unroll
                for (int r = 0; r < 4; ++r)
                    Out[(((size_t)(b * 16 + h) * 1024) + l0 + r) * 64 + kk] = (f16)(acc[mi][ni][r] * sc);
            } else {
                f16x4 hv;
#pragma unroll
                for (int r = 0; r < 4; ++r) hv[r] = (f16)acc[mi][ni][r];
                *(f16x4*)&Out[((size_t)(b * 16 + h) * 64 + kk) * 1024 + l0] = hv;
            }
        }
}

// ---------------- output projection GEMM: out0 = hc @ Wo^T + bo (f32, nt stores) --------
__global__ __launch_bounds__(256) void out_kernel(const f16* __restrict__ A,
        const f16* __restrict__ Bt, float* __restrict__ O, const float* __restrict__ bias) {
    __shared__ __align__(16) f16 As[128][64];
    __shared__ __align__(16) f16 Bs[128][64];
    const int id2 = blockIdx.x;
    const int m0 = ((id2 & 7) * 8 + ((id2 >> 3) & 7)) * 128;
    const int n0 = (id2 >> 6) * 128;
    const int tid = threadIdx.x, lane = tid & 63;
    const int w = tid >> 6, wr = w >> 1, wc = w & 1;

    f32x4 acc[4][4];
#pragma unroll
    for (int mi = 0; mi < 4; ++mi)
#pragma unroll
        for (int ni = 0; ni < 4; ++ni) acc[mi][ni] = (f32x4){0.f, 0.f, 0.f, 0.f};

    for (int kt = 0; kt < 16; ++kt) {
        const int k0 = kt * 64;
#pragma unroll
        for (int seg = 0; seg < 4; ++seg) {
            const int ch = seg * 256 + tid, r = ch >> 3, c = ch & 7;
            GLOAD_LDS16(&A[(size_t)(m0 + r) * 1024 + k0 + (c ^ (r & 7)) * 8],
                        (char*)&As[0][0] + (seg * 256 + w * 64) * 16);
            GLOAD_LDS16(&Bt[(size_t)(n0 + r) * 1024 + k0 + (c ^ (r & 7)) * 8],
                        (char*)&Bs[0][0] + (seg * 256 + w * 64) * 16);
        }
        __syncthreads();
#pragma unroll
        for (int ks = 0; ks < 2; ++ks) {
            const int slot = ks * 4 + (lane >> 4);
            f16x8 af[4], bf[4];
#pragma unroll
            for (int mi = 0; mi < 4; ++mi) {
                const int row = wr * 64 + mi * 16 + (lane & 15);
                af[mi] = *(const f16x8*)&As[row][(slot ^ (row & 7)) * 8];
            }
#pragma unroll
            for (int ni = 0; ni < 4; ++ni) {
                const int row = wc * 64 + ni * 16 + (lane & 15);
                bf[ni] = *(const f16x8*)&Bs[row][(slot ^ (row & 7)) * 8];
            }
#pragma unroll
            for (int mi = 0; mi < 4; ++mi)
#pragma unroll
                for (int ni = 0; ni < 4; ++ni)
                    acc[mi][ni] = __builtin_amdgcn_mfma_f32_16x16x32_f16(af[mi], bf[ni], acc[mi][ni], 0, 0, 0);
        }
        __syncthreads();
    }

#pragma unroll
    for (int mi = 0; mi < 4; ++mi)
#pragma unroll
        for (int ni = 0; ni < 4; ++ni) {
            const int row0 = m0 + wr * 64 + mi * 16 + ((lane >> 4) << 2);
            const int col = n0 + wc * 64 + ni * 16 + (lane & 15);
            const float bb = bias[col];
#pragma unroll
            for (int r = 0; r < 4; ++r)
                __builtin_nontemporal_store(acc[mi][ni][r] + bb, &O[(size_t)(row0 + r) * 1024 + col]);
        }
}

// ---------------- fused attention: 512 threads, Q-frags hoisted to registers ------------
__global__ __launch_bounds__(512, 4) void attn_fused_kernel(const f16* __restrict__ Qp,
        const f16* __restrict__ Kp, const f16* __restrict__ VpT,
        const unsigned* __restrict__ bits, float* __restrict__ attn, f16* __restrict__ headcat) {
    __shared__ __align__(16) f16 Qs[128][64];
    __shared__ __align__(16) f16 Ks[2][64][64];
    __shared__ __align__(16) f16 Vs[64][64];          // single buffer
    __shared__ __align__(16) f16 Ps[128][64];
    __shared__ unsigned bm[128][32];                  // word w stored at w ^ ((row&7)<<2)
    __shared__ __align__(16) float LUTf[16][4];
    __shared__ __align__(16) f16 LUTh[16][4];
    const int bh = blockIdx.x & 127, m0 = (blockIdx.x >> 7) * 128;
    const int b = bh >> 4, h = bh & 15;
    const int tid = threadIdx.x, lane = tid & 63, w = tid >> 6;  // w in [0,8)
    const int l15 = lane & 15, t4 = lane >> 4;
    const f16* Qbase = Qp + (size_t)bh * 65536;
    const f16* Kbase = Kp + (size_t)bh * 65536;
    const f16* Vbase = VpT + (size_t)bh * 65536;

    auto stageK = [&](int buf, int j) {      // 512 chunks, one per thread
        const int r = tid >> 3, c = tid & 7;
        GLOAD_LDS16(&Kbase[(size_t)(j * 64 + r) * 64 + (c ^ (r & 7)) * 8],
                    (char*)&Ks[buf][0][0] + (size_t)tid * 16);
    };
    auto stageV = [&](int j) {
        const int r = tid >> 3, c = tid & 7;
        GLOAD_LDS16(&Vbase[(size_t)r * 1024 + j * 64 + (c ^ (r & 7)) * 8],
                    (char*)&Vs[0][0] + (size_t)tid * 16);
    };

    if (tid < 16) {
#pragma unroll
        for (int i = 0; i < 4; ++i) {
            const float on = ((tid >> i) & 1) ? 1.0f : 0.0f;
            LUTf[tid][i] = on;
            LUTh[tid][i] = (f16)on;
        }
    }
    // prologue: Qs (16 KB), bm (16 KB, word-swizzled), K tile 0
#pragma unroll
    for (int seg = 0; seg < 2; ++seg) {
        const int ch = seg * 512 + tid, r = ch >> 3, c = ch & 7;
        GLOAD_LDS16(&Qbase[(size_t)(m0 + r) * 64 + (c ^ (r & 7)) * 8],
                    (char*)&Qs[0][0] + (size_t)ch * 16);
        GLOAD_LDS16((const char*)&bits[((size_t)b * 1024 + m0 + r) * 32] + (c ^ (r & 7)) * 16,
                    (char*)&bm[0][0] + (size_t)ch * 16);
    }
    stageK(0, 0);
    __syncthreads();

    const int rowm = w * 16 + l15;       // this thread's q-row (swapped S^T layout)
    const int swb = (rowm & 7) << 2;
    const int swp = (rowm & 7) << 3;
    const int kb0 = t4 * 4;              // contiguous 4-k-col base
    // Q fragments are loop-invariant: hoist once into registers (survive barriers)
    const f16x8 afA = *(const f16x8*)&Qs[rowm][(t4 ^ (rowm & 7)) * 8];
    const f16x8 afB = *(const f16x8*)&Qs[rowm][((4 + t4) ^ (rowm & 7)) * 8];
    float lsA = 0.f, lsB = 0.f;          // split accumulators (break fma chain)

    // -------- sweep 1: l = sum_col exp2(s) * mask --------
    for (int j = 0; j < 16; ++j) {
        if (j < 15) stageK((j + 1) & 1, j + 1);

        f32x4 acc[4];
#pragma unroll
        for (int ni = 0; ni < 4; ++ni) acc[ni] = (f32x4){0.f, 0.f, 0.f, 0.f};
#pragma unroll
        for (int ks = 0; ks < 2; ++ks) {
            const int slot = ks * 4 + t4;
            const f16x8 af = ks ? afB : afA;
#pragma unroll
            for (int ni = 0; ni < 4; ++ni) {
                const int row = ni * 16 + l15;
                const f16x8 bf = *(const f16x8*)&Ks[j & 1][row][(slot ^ (row & 7)) * 8];
                acc[ni] = __builtin_amdgcn_mfma_f32_16x16x32_f16(bf, af, acc[ni], 0, 0, 0);
            }
        }

#pragma unroll
        for (int ni = 0; ni < 4; ++ni) {
            const unsigned word = bm[rowm][(2 * j + (ni >> 1)) ^ swb];
            const unsigned nib = (word >> (((ni & 1) << 4) + kb0)) & 15u;
            const float4 mf = *(const float4*)&LUTf[nib][0];
            lsA = fmaf(exp2f(acc[ni][0]), mf.x, lsA);
            lsB = fmaf(exp2f(acc[ni][1]), mf.y, lsB);
            lsA = fmaf(exp2f(acc[ni][2]), mf.z, lsA);
            lsB = fmaf(exp2f(acc[ni][3]), mf.w, lsB);
        }
        __syncthreads();
    }

    // stage sweep-2 K tile 0 while reducing lsum
    stageK(0, 0);

    f16x2 rlp;
    {
        float s = lsA + lsB;
        s += __shfl_xor(s, 16);
        s += __shfl_xor(s, 32);
        const f16 rlh = (f16)(1.0f / s);
        rlp[0] = rlh; rlp[1] = rlh;
    }

    f32x4 accP[4];
#pragma unroll
    for (int ni = 0; ni < 4; ++ni) accP[ni] = (f32x4){0.f, 0.f, 0.f, 0.f};

    float* attnBase = attn + ((size_t)b * 1024 + m0) * 16384 + h * 1024;
    const int st_r0 = tid >> 4;       // store readback: row base (0..31)
    const int st_c4 = tid & 15;       // float4 column
    __syncthreads();

    // -------- sweep 2: recompute, normalized p -> Ps (packed); PV; store p from Ps --------
    for (int j = 0; j < 16; ++j) {
        if (j < 15) stageK((j + 1) & 1, j + 1);
        stageV(j);                    // single buffer; ready at mid-barrier

        f32x4 acc[4];
#pragma unroll
        for (int ni = 0; ni < 4; ++ni) acc[ni] = (f32x4){0.f, 0.f, 0.f, 0.f};
#pragma unroll
        for (int ks = 0; ks < 2; ++ks) {
            const int slot = ks * 4 + t4;
            const f16x8 af = ks ? afB : afA;
#pragma unroll
            for (int ni = 0; ni < 4; ++ni) {
                const int row = ni * 16 + l15;
                const f16x8 bf = *(const f16x8*)&Ks[j & 1][row][(slot ^ (row & 7)) * 8];
                acc[ni] = __builtin_amdgcn_mfma_f32_16x16x32_f16(bf, af, acc[ni], 0, 0, 0);
            }
        }

#pragma unroll
        for (int ni = 0; ni < 4; ++ni) {
            const unsigned word = bm[rowm][(2 * j + (ni >> 1)) ^ swb];
            const unsigned nib = (word >> (((ni & 1) << 4) + kb0)) & 15u;
            const f16x4 mh = *(const f16x4*)&LUTh[nib][0];
            f16x2 p01 = cvt_pk_f16(exp2f(acc[ni][0]), exp2f(acc[ni][1]));
            f16x2 p23 = cvt_pk_f16(exp2f(acc[ni][2]), exp2f(acc[ni][3]));
            p01 = p01 * (f16x2){mh[0], mh[1]} * rlp;
            p23 = p23 * (f16x2){mh[2], mh[3]} * rlp;
            f16x4 pw; pw[0] = p01[0]; pw[1] = p01[1]; pw[2] = p23[0]; pw[3] = p23[1];
            *(f16x4*)&Ps[rowm][(ni * 16 + kb0) ^ swp] = pw;
        }
        __syncthreads();   // Ps visible; Vs(j) drained

        // PV MFMA (normalized P)
#pragma unroll
        for (int ks = 0; ks < 2; ++ks) {
            const int slot = ks * 4 + t4;
            const f16x8 pf = *(const f16x8*)&Ps[rowm][(slot ^ (rowm & 7)) * 8];
#pragma unroll
            for (int ni = 0; ni < 4; ++ni) {
                const int row = ni * 16 + l15;
                const f16x8 vf = *(const f16x8*)&Vs[row][(slot ^ (row & 7)) * 8];
                accP[ni] = __builtin_amdgcn_mfma_f32_16x16x32_f16(pf, vf, accP[ni], 0, 0, 0);
            }
        }

        // coalesced p store from Ps (256B per 16 lanes), overlaps MFMA
#pragma unroll
        for (int i = 0; i < 4; ++i) {
            const int row = st_r0 + 32 * i;
            const f16x4 hv = *(const f16x4*)((const char*)&Ps[row][0] +
                    ((st_c4 >> 1) ^ (row & 7)) * 16 + (st_c4 & 1) * 8);
            f32x4 fv = {(float)hv[0], (float)hv[1], (float)hv[2], (float)hv[3]};
            __builtin_nontemporal_store(fv,
                    (f32x4*)&attnBase[(size_t)row * 16384 + j * 64 + st_c4 * 4]);
        }
        __syncthreads();
    }

#pragma unroll
    for (int ni = 0; ni < 4; ++ni) {
        const int row0 = m0 + w * 16 + (t4 << 2);
        const int col = ni * 16 + l15;
#pragma unroll
        for (int r = 0; r < 4; ++r)
            headcat[((size_t)b * 1024 + row0 + r) * 1024 + h * 64 + col] = (f16)accP[ni][r];
    }
}

extern "C" void kernel_launch(void* const* d_in, const int* in_sizes, int n_in,
                              void* d_out, int out_size, void* d_ws, size_t ws_size,
                              hipStream_t stream) {
    const float* q = (const float*)d_in[0];
    const float* k = (const float*)d_in[1];
    const float* v = (const float*)d_in[2];
    const int* mask = (const int*)d_in[3];
    const float* Wq = (const float*)d_in[4];
    const float* Wk = (const float*)d_in[5];
    const float* Wv = (const float*)d_in[6];
    const float* Wo = (const float*)d_in[7];
    const float* bo = (const float*)d_in[8];

    float* out0 = (float*)d_out;                  // [8,1024,1024]
    float* attn = out0 + (size_t)8 * 1024 * 1024; // [8,1024,16384]

    char* ws = (char*)d_ws;
    f16* wt   = (f16*)(ws + ((size_t)0 << 20));   // wqt,wkt,wvt,wot contiguous: 8 MiB
    f16* qh   = (f16*)(ws + ((size_t)8 << 20));   // q,k,v f16 contiguous: 48 MiB
    f16* Qp   = (f16*)(ws + ((size_t)56 << 20));  // Qp,Kp,VpT contiguous: 48 MiB
    f16* Kp   = (f16*)(ws + ((size_t)72 << 20));
    f16* VpT  = (f16*)(ws + ((size_t)88 << 20));
    f16* hc   = (f16*)(ws + ((size_t)104 << 20)); // [B*L, 1024] f16
    unsigned* bits = (unsigned*)(ws + ((size_t)120 << 20)); // 1 MiB bitmask
    f16* wot  = wt + (size_t)3 * 1048576;

    prep_kernel<<<13312, 256, 0, stream>>>(q, k, v, Wq, Wk, Wv, Wo, qh, wt);

    proj_kernel<<<2560, 256, 0, stream>>>(qh, wt, Qp, mask, bits);

    attn_fused_kernel<<<1024, 512, 0, stream>>>(Qp, Kp, VpT, bits, attn, hc);

    out_kernel<<<512, 256, 0, stream>>>(hc, wot, out0, bo);
}